// Round 4
// baseline (93326.099 us; speedup 1.0000x reference)
//
#include <hip/hip_runtime.h>
#include <math.h>

// dims
#define BB 32
#define MM 64
#define LL 512
#define TT 96
#define PP 8
#define SS 4
#define DD 64
#define NN 128
#define RDIM 128   // R*D
#define CH 16      // M-chunk for h buffer
#define HROWS 19   // CH + 3 halo rows (conv2 reads m-1..m+2)
#define BC 4       // batch chunk (ws ~= 21.8 MB fp32)

// ---------------------------------------------------------------------------
// embed: x [B*M, L] -> X [BC*M, N, D]   (conv1d k=8 stride=4, edge-pad right 4)
// ---------------------------------------------------------------------------
__global__ __launch_bounds__(256) void embed_kernel(
    const float* __restrict__ x,
    const float* __restrict__ w,    // [D, P]
    const float* __restrict__ bias, // [D]
    float* __restrict__ xe,         // ws, [BC*M, N, D]
    int bm_off) {
  int tid = blockIdx.x * 256 + threadIdx.x;  // BC*M*N*D total
  int d  = tid & (DD - 1);
  int n  = (tid >> 6) & (NN - 1);
  int bm = tid >> 13;                        // local bm in [0, BC*M)
  const float* xr = x + (size_t)(bm_off + bm) * LL;
  float acc = bias[d];
  int base = n * SS;
#pragma unroll
  for (int p = 0; p < PP; ++p) {
    int i = base + p;
    if (i > LL - 1) i = LL - 1;   // edge pad (right, 4)
    acc += w[d * PP + p] * xr[i];
  }
  xe[tid] = acc;
}

// ---------------------------------------------------------------------------
// depthwise conv over M (k=4, pad left 1 right 2), channel c = n*D + d
// in/out layout [BC, M, N, D] (both in ws)
// ---------------------------------------------------------------------------
__global__ __launch_bounds__(256) void dw_kernel(
    const float* __restrict__ xe,
    const float* __restrict__ w,    // [N*D, 4]
    const float* __restrict__ bias, // [N*D]
    float* __restrict__ out) {
  int tid = blockIdx.x * 256 + threadIdx.x;
  int d = tid & (DD - 1);
  int n = (tid >> 6) & (NN - 1);
  int m = (tid >> 13) & (MM - 1);
  int b = tid >> 19;                         // local b in [0, BC)
  int c = n * DD + d;
  float acc = bias[c];
#pragma unroll
  for (int k = 0; k < 4; ++k) {
    int mm2 = m - 1 + k;
    if (mm2 >= 0 && mm2 < MM)
      acc += w[c * 4 + k] * xe[((size_t)(b * MM + mm2) * NN + n) * DD + d];
  }
  out[tid] = acc;
}

// ---------------------------------------------------------------------------
// conv2d (kernel 4x3 over (M,N), pad M:(1,2) N:(1,1)) + optional GELU/residual
// Row-windowed: covers global out rows [m_out0, m_out0+rows), b in [0, BC).
// out/resid may alias (in-place residual) -> NOT __restrict__.
// ---------------------------------------------------------------------------
template <int CIN, int COUT, int NTILE, int TCO, bool GELU, bool RESID>
__global__ __launch_bounds__(256) void conv_kernel(
    const float* __restrict__ in,
    const float* __restrict__ w,     // [COUT, CIN, 4, 3]
    const float* __restrict__ bias,  // [COUT]
    const float* resid,              // [BC, MM, N, COUT] (may alias out)
    float* out,
    int m_out0, int rows, int in_base, int in_alloc, int out_base, int out_alloc) {
  constexpr int CO_T = COUT / TCO;
  constexpr int N_T = NTILE / 4;
  static_assert(CO_T * N_T == 256, "block mapping");
  constexpr int NBLK = NN / NTILE;
  constexpr int WSTRIDE = CIN * 12;  // elems between consecutive co rows

  __shared__ float lds[(NTILE + 2) * CIN];

  int blk = blockIdx.x;
  int nb = blk % NBLK;
  int t = blk / NBLK;
  int mi = t % rows;
  int b = t / rows;
  int m = m_out0 + mi;
  int n0 = nb * NTILE;

  int tid = threadIdx.x;
  int co_t = tid % CO_T;
  int n_t = tid / CO_T;
  int co0 = co_t * TCO;
  int nbase = n_t * 4;

  float acc[4][TCO];
#pragma unroll
  for (int j = 0; j < 4; ++j)
#pragma unroll
    for (int c = 0; c < TCO; ++c) acc[j][c] = 0.f;

  for (int dm = 0; dm < 4; ++dm) {
    int row = m - 1 + dm;                       // global input row
    bool rowok = (row >= 0 && row < MM);
    int lrow = rowok ? (row - in_base) : 0;     // local row in `in` buffer
    const float4* src = (const float4*)(
        in + (size_t)(b * in_alloc + lrow) * NN * CIN);
    constexpr int QUADS = (NTILE + 2) * CIN / 4;
    for (int p = tid; p < QUADS; p += 256) {
      int col = p / (CIN / 4);
      int n = n0 - 1 + col;
      float4 v = make_float4(0.f, 0.f, 0.f, 0.f);
      if (rowok && n >= 0 && n < NN) v = src[(size_t)n * (CIN / 4) + (p % (CIN / 4))];
      ((float4*)lds)[p] = v;
    }
    __syncthreads();

    for (int dn = 0; dn < 3; ++dn) {
      const float* wp = w + (size_t)co0 * WSTRIDE + dm * 3 + dn;
      for (int ci = 0; ci < CIN; ++ci) {
        float inv[4];
#pragma unroll
        for (int j = 0; j < 4; ++j)
          inv[j] = lds[(nbase + j + dn) * CIN + ci];
#pragma unroll
        for (int c = 0; c < TCO; ++c) {
          float wv = wp[(size_t)c * WSTRIDE + ci * 12];
#pragma unroll
          for (int j = 0; j < 4; ++j) acc[j][c] += inv[j] * wv;
        }
      }
    }
    __syncthreads();
  }

  size_t obase = ((size_t)(b * out_alloc + (m - out_base)) * NN + n0 + nbase) * COUT;
  size_t rbase = ((size_t)(b * MM + m) * NN + n0 + nbase) * COUT;
#pragma unroll
  for (int j = 0; j < 4; ++j) {
#pragma unroll
    for (int c = 0; c < TCO; ++c) {
      float v = acc[j][c] + bias[co0 + c];
      if (GELU) v = 0.5f * v * (1.0f + erff(v * 0.70710678118654752f));
      if (RESID) v += resid[rbase + (size_t)j * COUT + co0 + c];
      out[obase + (size_t)j * COUT + co0 + c] = v;
    }
  }
}

// ---------------------------------------------------------------------------
// head: out[bm, t] = sum_f X[bm, f] * hw[t, f] + hb[t],  f = d*N + n
// X local [BC*M, N, D]; out global via bm_off.
// ---------------------------------------------------------------------------
__global__ __launch_bounds__(512) void head_kernel(
    const float* __restrict__ xe,
    const float* __restrict__ hw,   // [T, D*N]
    const float* __restrict__ hb,   // [T]
    float* __restrict__ out,
    int bm_off) {
  __shared__ float z[DD * 129];  // z[d*129 + n], +1 pad breaks bank conflicts
  int bm = blockIdx.x;
  int tid = threadIdx.x;
  const float* src = xe + (size_t)bm * DD * NN;
  for (int i = tid; i < DD * NN; i += 512) {
    int n = i >> 6;          // i = n*DD + d
    int d = i & (DD - 1);
    z[d * 129 + n] = src[i];
  }
  __syncthreads();
  int wave = tid >> 6;
  int lane = tid & 63;
  for (int tt = 0; tt < 12; ++tt) {
    int t = wave * 12 + tt;
    const float* wr = hw + (size_t)t * DD * NN;
    float acc = 0.f;
    for (int k = 0; k < DD; ++k) {   // f = k*128 + {lane, lane+64}
      acc += z[k * 129 + lane] * wr[k * 128 + lane];
      acc += z[k * 129 + lane + 64] * wr[k * 128 + lane + 64];
    }
#pragma unroll
    for (int off = 32; off > 0; off >>= 1) acc += __shfl_down(acc, off, 64);
    if (lane == 0)
      out[(size_t)(bm_off + bm) * TT + t] = acc + hb[t];
  }
}

// ---------------------------------------------------------------------------
extern "C" void kernel_launch(void* const* d_in, const int* in_sizes, int n_in,
                              void* d_out, int out_size, void* d_ws, size_t ws_size,
                              hipStream_t stream) {
  const float* x      = (const float*)d_in[0];
  const float* emb_w  = (const float*)d_in[1];
  const float* emb_b  = (const float*)d_in[2];
  const float* head_w = (const float*)d_in[3];
  const float* head_b = (const float*)d_in[4];
  const float* dw_w1  = (const float*)d_in[5];
  const float* dw_b1  = (const float*)d_in[6];
  const float* f11_w  = (const float*)d_in[7];
  const float* f11_b  = (const float*)d_in[8];
  const float* f12_w  = (const float*)d_in[9];
  const float* f12_b  = (const float*)d_in[10];
  const float* dw_w2  = (const float*)d_in[11];
  const float* dw_b2  = (const float*)d_in[12];
  const float* f21_w  = (const float*)d_in[13];
  const float* f21_b  = (const float*)d_in[14];
  const float* f22_w  = (const float*)d_in[15];
  const float* f22_b  = (const float*)d_in[16];

  // ws (per batch-chunk BC=4): X 2.10M + Y 2.10M + H 1.25M fp32 = 21.8 MB
  const size_t X_ELEMS = (size_t)BC * MM * NN * DD;        // 2,097,152
  float* X = (float*)d_ws;
  float* Y = X + X_ELEMS;
  float* H = Y + X_ELEMS;
  (void)ws_size;

  const int EL_BLOCKS = (int)(X_ELEMS / 256);              // 8192

  for (int g = 0; g < BB / BC; ++g) {
    int bm_off = g * BC * MM;

    embed_kernel<<<EL_BLOCKS, 256, 0, stream>>>(x, emb_w, emb_b, X, bm_off);

    for (int blkI = 0; blkI < 2; ++blkI) {
      const float* dw_w = blkI ? dw_w2 : dw_w1;
      const float* dw_b = blkI ? dw_b2 : dw_b1;
      const float* f1w  = blkI ? f21_w : f11_w;
      const float* f1b  = blkI ? f21_b : f11_b;
      const float* f2w  = blkI ? f22_w : f12_w;
      const float* f2b  = blkI ? f22_b : f12_b;

      dw_kernel<<<EL_BLOCKS, 256, 0, stream>>>(X, dw_w, dw_b, Y);

      for (int c = 0; c < MM / CH; ++c) {
        int hbase = c * CH - 1;                       // local h row = m - hbase
        int h0 = hbase < 0 ? 0 : hbase;               // first valid h row
        int h1 = c * CH + CH + 2; if (h1 > MM) h1 = MM;
        int hrows = h1 - h0;
        // conv1 + GELU: Y rows -> H chunk rows [h0, h1)
        conv_kernel<DD, RDIM, 64, 8, true, false>
            <<<BC * hrows * (NN / 64), 256, 0, stream>>>(
                Y, f1w, f1b, nullptr, H,
                /*m_out0*/ h0, /*rows*/ hrows,
                /*in_base*/ 0, /*in_alloc*/ MM,
                /*out_base*/ hbase, /*out_alloc*/ HROWS);
        // conv2 + residual (in place on X): H chunk -> X rows [c*CH, c*CH+CH)
        conv_kernel<RDIM, DD, 64, 4, false, true>
            <<<BC * CH * (NN / 64), 256, 0, stream>>>(
                H, f2w, f2b, X, X,
                /*m_out0*/ c * CH, /*rows*/ CH,
                /*in_base*/ hbase, /*in_alloc*/ HROWS,
                /*out_base*/ 0, /*out_alloc*/ MM);
      }
    }

    head_kernel<<<BC * MM, 512, 0, stream>>>(X, head_w, head_b,
                                             (float*)d_out, bm_off);
  }
}

// Round 5
// 1158.040 us; speedup vs baseline: 80.5897x; 80.5897x over previous
//
#include <hip/hip_runtime.h>
#include <hip/hip_bf16.h>
#include <math.h>

// dims
#define MMX 64
#define NNX 128
#define DDX 64
#define RDX 128
#define TTX 96
#define LLX 512

typedef short bfx8 __attribute__((ext_vector_type(8)));
typedef float floatx4 __attribute__((ext_vector_type(4)));

__device__ __forceinline__ unsigned short f2bs(float v) {
  __hip_bfloat16 t = __float2bfloat16(v);
  return *reinterpret_cast<unsigned short*>(&t);
}
__device__ __forceinline__ float gelu(float v) {
  return 0.5f * v * (1.0f + erff(v * 0.70710678118654752f));
}

// ---------------------------------------------------------------------------
// prep: conv weight fp32 [CO][CI][4][3] -> bf16 [dd=dm*3+dn][co][ci]
// ---------------------------------------------------------------------------
__global__ __launch_bounds__(256) void castw_kernel(
    const float* __restrict__ w, __hip_bfloat16* __restrict__ o, int CO, int CI) {
  int i = blockIdx.x * 256 + threadIdx.x;      // CO*CI*12 total
  int ci = i % CI;
  int t = i / CI;
  int co = t % CO;
  int dd = t / CO;
  o[i] = __float2bfloat16(w[(size_t)(co * CI + ci) * 12 + dd]);
}

// ---------------------------------------------------------------------------
// prep: head weight fp32 [96][f=d*128+n] -> bf16 [96][fh=n*64+d]
// ---------------------------------------------------------------------------
__global__ __launch_bounds__(256) void headw_kernel(
    const float* __restrict__ hw, __hip_bfloat16* __restrict__ o) {
  int i = blockIdx.x * 256 + threadIdx.x;      // 96*8192 total
  int fh = i & 8191;
  int t = i >> 13;
  int d = fh & 63;
  int n = fh >> 6;
  o[i] = __float2bfloat16(hw[(size_t)t * 8192 + d * 128 + n]);
}

// ---------------------------------------------------------------------------
// embed: x [B*M, L] fp32 -> X [Bc*M, N, D] fp32 (k=8 stride=4, edge-pad right)
// ---------------------------------------------------------------------------
__global__ __launch_bounds__(256) void embed_kernel(
    const float* __restrict__ x, const float* __restrict__ w,
    const float* __restrict__ bias, float* __restrict__ xe, int bm_off) {
  int tid = blockIdx.x * 256 + threadIdx.x;
  int d  = tid & 63;
  int n  = (tid >> 6) & 127;
  int bm = tid >> 13;
  const float* xr = x + (size_t)(bm_off + bm) * LLX;
  float acc = bias[d];
  int base = n * 4;
#pragma unroll
  for (int p = 0; p < 8; ++p) {
    int i = base + p;
    if (i > LLX - 1) i = LLX - 1;
    acc += w[d * 8 + p] * xr[i];
  }
  xe[tid] = acc;
}

// ---------------------------------------------------------------------------
// depthwise conv over M (k=4, zero-pad 1/2): X fp32 -> Y bf16, layout [b,m,n,d]
// ---------------------------------------------------------------------------
__global__ __launch_bounds__(256) void dw_kernel(
    const float* __restrict__ xe, const float* __restrict__ w,
    const float* __restrict__ bias, __hip_bfloat16* __restrict__ out) {
  int tid = blockIdx.x * 256 + threadIdx.x;
  int d = tid & 63;
  int n = (tid >> 6) & 127;
  int m = (tid >> 13) & 63;
  int b = tid >> 19;
  int c = n * DDX + d;
  float acc = bias[c];
#pragma unroll
  for (int k = 0; k < 4; ++k) {
    int mm2 = m - 1 + k;
    if (mm2 >= 0 && mm2 < MMX)
      acc += w[c * 4 + k] * xe[((size_t)(b * MMX + mm2) * NNX + n) * DDX + d];
  }
  out[tid] = __float2bfloat16(acc);
}

// ---------------------------------------------------------------------------
// MFMA conv2d 4x3, pad M(1,2) N(1,1). One block = one (b,m) row, 128 px x COUT.
// in bf16 [b,64,128,CIN]; wT bf16 [12][COUT][CIN]; bias fp32.
// GELU: out = hout bf16.  RESID: out = xio fp32 += residual (in-place on X).
// 4 waves: (w>>1) -> pixel half (64), (w&1) -> co half.
// ---------------------------------------------------------------------------
template <int CIN, int COUT, bool GELU, bool RESID>
__global__ __launch_bounds__(256) void conv_mfma(
    const __hip_bfloat16* __restrict__ in,
    const __hip_bfloat16* __restrict__ wT,
    const float* __restrict__ bias,
    float* xio,
    __hip_bfloat16* __restrict__ hout) {
  constexpr int ISTR = CIN + 8;   // bf16 elems/row; (ISTR*2/4)/4 odd -> balanced banks
  constexpr int WSTR = CIN + 8;
  constexpr int PT = 4;           // 4 pixel tiles of 16 per wave (64 px)
  constexpr int CT = COUT / 32;   // co tiles of 16 per wave
  constexpr int KC = CIN / 32;
  __shared__ unsigned short ilds[130 * ISTR];
  __shared__ unsigned short wlds[COUT * WSTR];

  const int blk = blockIdx.x;
  const int m = blk & 63;
  const int b = blk >> 6;
  const int tid = threadIdx.x;
  const int lane = tid & 63;
  const int w = tid >> 6;
  const int wp0 = (w >> 1) * 64;
  const int wc0 = (w & 1) * (COUT / 2);
  const int l15 = lane & 15;
  const int quad = lane >> 4;

  floatx4 acc[PT][CT];
#pragma unroll
  for (int i = 0; i < PT; ++i)
#pragma unroll
    for (int j = 0; j < CT; ++j) acc[i][j] = (floatx4)0.f;

  for (int dm = 0; dm < 4; ++dm) {
    int row = m - 1 + dm;
    bool rowok = (row >= 0 && row < MMX);
    __syncthreads();  // prior K-loop reads (ilds+wlds) done before restage
    {   // stage input row -> ilds[nn][ci], nn = n+1 (2 halo cols zero)
      const uint4* src = (const uint4*)(
          in + (size_t)(b * MMX + (rowok ? row : 0)) * NNX * CIN);
      constexpr int IV = CIN / 8;
      constexpr int TOTI = 130 * IV;
      for (int idx = tid; idx < TOTI; idx += 256) {
        int nn = idx / IV, cg = idx % IV;
        int n = nn - 1;
        uint4 v = make_uint4(0u, 0u, 0u, 0u);
        if (rowok && n >= 0 && n < NNX) v = src[n * IV + cg];
        *(uint4*)&ilds[nn * ISTR + cg * 8] = v;
      }
    }
    for (int dn = 0; dn < 3; ++dn) {
      if (dn) __syncthreads();  // K-loop reads of prev wlds done
      {  // stage weights (dm,dn) -> wlds[co][ci]
        const uint4* wsrc = (const uint4*)(wT + (size_t)(dm * 3 + dn) * COUT * CIN);
        constexpr int WV = CIN / 8;
        constexpr int TOTW = COUT * WV;
        for (int idx = tid; idx < TOTW; idx += 256) {
          int co = idx / WV, cg = idx % WV;
          *(uint4*)&wlds[co * WSTR + cg * 8] = wsrc[idx];
        }
      }
      __syncthreads();
#pragma unroll
      for (int kc = 0; kc < KC; ++kc) {
        const int kb = kc * 32 + quad * 8;
        bfx8 a[PT];
#pragma unroll
        for (int i = 0; i < PT; ++i)
          a[i] = *(const bfx8*)&ilds[(wp0 + 16 * i + l15 + dn) * ISTR + kb];
#pragma unroll
        for (int j = 0; j < CT; ++j) {
          bfx8 bv = *(const bfx8*)&wlds[(wc0 + 16 * j + l15) * WSTR + kb];
#pragma unroll
          for (int i = 0; i < PT; ++i)
            acc[i][j] = __builtin_amdgcn_mfma_f32_16x16x32_bf16(
                a[i], bv, acc[i][j], 0, 0, 0);
        }
      }
    }
  }

  // epilogue: D row (pixel) = quad*4+r, col (co) = l15
  size_t rowbase = (size_t)(b * MMX + m) * NNX;
#pragma unroll
  for (int j = 0; j < CT; ++j) {
    int co = wc0 + 16 * j + l15;
    float bv = bias[co];
#pragma unroll
    for (int i = 0; i < PT; ++i) {
#pragma unroll
      for (int r = 0; r < 4; ++r) {
        int p = wp0 + 16 * i + quad * 4 + r;
        float v = acc[i][j][r] + bv;
        size_t idx = (rowbase + p) * COUT + co;
        if (GELU) {
          hout[idx] = __float2bfloat16(gelu(v));
        } else if (RESID) {
          xio[idx] = v + xio[idx];
        }
      }
    }
  }
}

// ---------------------------------------------------------------------------
// MFMA head: out[bm,t] = sum_f X[bm,fh] * hwT[t,fh] + hb[t]   (fh = n*64+d)
// block = 32 bm x 96 t; 4 waves: (w>>1)->bm half 16, (w&1)->t half 48 (3 tiles)
// ---------------------------------------------------------------------------
__global__ __launch_bounds__(256) void head_mfma(
    const float* __restrict__ X,              // [Bc*64, 8192]
    const __hip_bfloat16* __restrict__ hwT,   // [96, 8192] bf16
    const float* __restrict__ hb,
    float* __restrict__ out, int bm_off) {
  __shared__ unsigned short alds[32 * 72];
  __shared__ unsigned short blds[96 * 72];
  const int bm0 = blockIdx.x * 32;
  const int tid = threadIdx.x;
  const int lane = tid & 63;
  const int w = tid >> 6;
  const int wbm = w >> 1;
  const int wt0 = (w & 1) * 48;
  const int l15 = lane & 15;
  const int quad = lane >> 4;

  floatx4 acc[3];
#pragma unroll
  for (int j = 0; j < 3; ++j) acc[j] = (floatx4)0.f;

  for (int k0 = 0; k0 < 8192; k0 += 64) {
    __syncthreads();
    for (int idx = tid; idx < 2048; idx += 256) {     // A: 32 bm x 64 k, cast
      int i = idx >> 6, k = idx & 63;
      alds[i * 72 + k] = f2bs(X[(size_t)(bm0 + i) * 8192 + k0 + k]);
    }
    for (int idx = tid; idx < 768; idx += 256) {      // B: 96 t x 64 k
      int t = idx >> 3, cg = idx & 7;
      *(uint4*)&blds[t * 72 + cg * 8] =
          ((const uint4*)(hwT + (size_t)t * 8192 + k0))[cg];
    }
    __syncthreads();
#pragma unroll
    for (int kc = 0; kc < 2; ++kc) {
      const int kb = kc * 32 + quad * 8;
      bfx8 a = *(const bfx8*)&alds[(wbm * 16 + l15) * 72 + kb];
#pragma unroll
      for (int j = 0; j < 3; ++j) {
        bfx8 bv = *(const bfx8*)&blds[(wt0 + 16 * j + l15) * 72 + kb];
        acc[j] = __builtin_amdgcn_mfma_f32_16x16x32_bf16(a, bv, acc[j], 0, 0, 0);
      }
    }
  }
#pragma unroll
  for (int j = 0; j < 3; ++j) {
    int t = wt0 + 16 * j + l15;
    float bt = hb[t];
#pragma unroll
    for (int r = 0; r < 4; ++r) {
      int bm = bm0 + wbm * 16 + quad * 4 + r;
      out[(size_t)(bm_off + bm) * TTX + t] = acc[j][r] + bt;
    }
  }
}

// ---------------------------------------------------------------------------
extern "C" void kernel_launch(void* const* d_in, const int* in_sizes, int n_in,
                              void* d_out, int out_size, void* d_ws, size_t ws_size,
                              hipStream_t stream) {
  const float* x      = (const float*)d_in[0];
  const float* emb_w  = (const float*)d_in[1];
  const float* emb_b  = (const float*)d_in[2];
  const float* head_w = (const float*)d_in[3];
  const float* head_b = (const float*)d_in[4];
  const float* dw_w1  = (const float*)d_in[5];
  const float* dw_b1  = (const float*)d_in[6];
  const float* f11_w  = (const float*)d_in[7];
  const float* f11_b  = (const float*)d_in[8];
  const float* f12_w  = (const float*)d_in[9];
  const float* f12_b  = (const float*)d_in[10];
  const float* dw_w2  = (const float*)d_in[11];
  const float* dw_b2  = (const float*)d_in[12];
  const float* f21_w  = (const float*)d_in[13];
  const float* f21_b  = (const float*)d_in[14];
  const float* f22_w  = (const float*)d_in[15];
  const float* f22_b  = (const float*)d_in[16];

  // ws layout: 4 conv wT (bf16, 98304 each) | hwT (bf16, 786432) | X | Y | H
  const size_t WEL = 98304, HWEL = 786432;
  __hip_bfloat16* wt11 = (__hip_bfloat16*)d_ws;
  __hip_bfloat16* wt12 = wt11 + WEL;
  __hip_bfloat16* wt21 = wt12 + WEL;
  __hip_bfloat16* wt22 = wt21 + WEL;
  __hip_bfloat16* hwT  = wt22 + WEL;
  char* dyn = (char*)(hwT + HWEL);
  const size_t fixed_bytes = (4 * WEL + HWEL) * 2;

  // batch chunk: per-b bytes = X 2.097M(fp32) + Y 1.049M(bf16) + H 2.097M(bf16)
  const size_t PER_B = 5242880;
  int Bc = 32;
  while (Bc > 1 && fixed_bytes + (size_t)Bc * PER_B > ws_size) Bc >>= 1;

  float* X = (float*)dyn;
  __hip_bfloat16* Y = (__hip_bfloat16*)(dyn + (size_t)Bc * 2097152);
  __hip_bfloat16* H = (__hip_bfloat16*)(dyn + (size_t)Bc * (2097152 + 1048576));

  // prep (once per launch)
  castw_kernel<<<384, 256, 0, stream>>>(f11_w, wt11, RDX, DDX);
  castw_kernel<<<384, 256, 0, stream>>>(f12_w, wt12, DDX, RDX);
  castw_kernel<<<384, 256, 0, stream>>>(f21_w, wt21, RDX, DDX);
  castw_kernel<<<384, 256, 0, stream>>>(f22_w, wt22, DDX, RDX);
  headw_kernel<<<3072, 256, 0, stream>>>(head_w, hwT);

  for (int b0 = 0; b0 < 32; b0 += Bc) {
    int bm_off = b0 * MMX;
    embed_kernel<<<Bc * 2048, 256, 0, stream>>>(x, emb_w, emb_b, X, bm_off);

    for (int l = 0; l < 2; ++l) {
      const float* dwW = l ? dw_w2 : dw_w1;
      const float* dwB = l ? dw_b2 : dw_b1;
      const __hip_bfloat16* w1 = l ? wt21 : wt11;
      const float* b1 = l ? f21_b : f11_b;
      const __hip_bfloat16* w2 = l ? wt22 : wt12;
      const float* b2 = l ? f22_b : f12_b;

      dw_kernel<<<Bc * 2048, 256, 0, stream>>>(X, dwW, dwB, Y);
      conv_mfma<DDX, RDX, true, false>
          <<<Bc * MMX, 256, 0, stream>>>(Y, w1, b1, nullptr, H);
      conv_mfma<RDX, DDX, false, true>
          <<<Bc * MMX, 256, 0, stream>>>(H, w2, b2, X, nullptr);
    }

    head_mfma<<<Bc * 2, 256, 0, stream>>>(X, hwT, head_b, (float*)d_out, bm_off);
  }
}